// Round 1
// baseline (1597.985 us; speedup 1.0000x reference)
//
#include <hip/hip_runtime.h>

#define DIM 768
#define NHEADS 12
#define HDIM 64
#define BB 16
#define NN 784
#define M_TOTAL (BB * NN)   // 12544

// ---------------------------------------------------------------------------
// Generic f32 GEMM + bias: C[M,N] = A[M,K] @ B[K,N] + bias[N]
// 128x128 block tile, BK=8, 256 threads, 8x8 microtile per thread.
// All dims divisible by tile sizes for our shapes (12544/128=98, 2304/128=18,
// 768/128=6, K=768/8=96).
// ---------------------------------------------------------------------------
template <int BM, int BN, int BK>
__global__ __launch_bounds__(256) void gemm_bias_kernel(
    const float* __restrict__ A, const float* __restrict__ B,
    const float* __restrict__ bias, float* __restrict__ C,
    int M, int N, int K)
{
    __shared__ float As[BK][BM];   // A tile stored transposed: [k][m]
    __shared__ float Bs[BK][BN];   // [k][n]

    const int tid = threadIdx.x;
    const int gm = blockIdx.y * BM;
    const int gn = blockIdx.x * BN;
    const int tx = tid % 16;   // column group (8 cols each)
    const int ty = tid / 16;   // row group (8 rows each)

    // global-load mapping
    const int ar = tid / 2;          // 0..127  (A row within tile)
    const int ac = (tid % 2) * 4;    // 0 or 4  (A col within BK=8)
    const int br = tid / 32;         // 0..7    (B row within BK)
    const int bc = (tid % 32) * 4;   // 0..124  (B col within tile)

    float acc[8][8] = {};

    for (int k0 = 0; k0 < K; k0 += BK) {
        float4 av = *(const float4*)&A[(size_t)(gm + ar) * K + k0 + ac];
        float4 bv = *(const float4*)&B[(size_t)(k0 + br) * N + gn + bc];
        __syncthreads();  // previous iteration's readers done
        As[ac + 0][ar] = av.x;
        As[ac + 1][ar] = av.y;
        As[ac + 2][ar] = av.z;
        As[ac + 3][ar] = av.w;
        *(float4*)&Bs[br][bc] = bv;
        __syncthreads();

#pragma unroll
        for (int k = 0; k < BK; ++k) {
            float4 a0 = *(const float4*)&As[k][ty * 8];
            float4 a1 = *(const float4*)&As[k][ty * 8 + 4];
            float4 b0 = *(const float4*)&Bs[k][tx * 8];
            float4 b1 = *(const float4*)&Bs[k][tx * 8 + 4];
            float a[8] = {a0.x, a0.y, a0.z, a0.w, a1.x, a1.y, a1.z, a1.w};
            float b[8] = {b0.x, b0.y, b0.z, b0.w, b1.x, b1.y, b1.z, b1.w};
#pragma unroll
            for (int i = 0; i < 8; ++i)
#pragma unroll
                for (int j = 0; j < 8; ++j)
                    acc[i][j] += a[i] * b[j];
        }
    }

    // epilogue with bias
#pragma unroll
    for (int i = 0; i < 8; ++i) {
        const int row = gm + ty * 8 + i;
#pragma unroll
        for (int j = 0; j < 8; j += 4) {
            const int col = gn + tx * 8 + j;
            float4 bv = *(const float4*)&bias[col];
            float4 o;
            o.x = acc[i][j + 0] + bv.x;
            o.y = acc[i][j + 1] + bv.y;
            o.z = acc[i][j + 2] + bv.z;
            o.w = acc[i][j + 3] + bv.w;
            *(float4*)&C[(size_t)row * N + col] = o;
        }
    }
}

// ---------------------------------------------------------------------------
// Flash-style attention, f32.
// Block = 256 threads handles one (batch, head, 32 q-rows).
// Thread (r = tid/8, c = tid%8): owns row r, output dims d = c*8 .. c*8+7.
// j-tiles of 64 keys; online softmax (m, l per row, replicated across the
// row's 8 lanes via 8-lane butterfly shuffles).
// LDS strides padded to 68 floats (17 float4s): keeps float4 alignment and
// makes Qs[r][d] / Ps[r][j] per-row scalar reads conflict-free
// (bank = (4*r + idx) % 32 spreads 8 rows over 8 banks).
// ---------------------------------------------------------------------------
#define ATS 68  // padded LDS stride

__global__ __launch_bounds__(256) void attn_kernel(
    const float* __restrict__ qkv, float* __restrict__ out)
{
    const int b = blockIdx.z;
    const int h = blockIdx.y;
    const int q0 = blockIdx.x * 32;
    const int tid = threadIdx.x;
    const int r = tid / 8;   // local q row 0..31
    const int c = tid % 8;   // dim/key group 0..7

    __shared__ float Qs[32][ATS];    // [r][d]
    __shared__ float Kts[64][ATS];   // transposed: [d][j]
    __shared__ float Vs[64][ATS];    // [j][d]
    __shared__ float Ps[32][ATS];    // [r][j]

    const float scale = 0.125f;  // 1/sqrt(64)

    // ---- load Q tile (rows >= 784 clamp to 783; their output is discarded)
    {
        int qrow = q0 + r;
        if (qrow > NN - 1) qrow = NN - 1;
        size_t base = ((size_t)(b * NN + qrow) * 3 + 0) * DIM + h * HDIM + c * 8;
        float4 v0 = *(const float4*)&qkv[base];
        float4 v1 = *(const float4*)&qkv[base + 4];
        *(float4*)&Qs[r][c * 8] = v0;
        *(float4*)&Qs[r][c * 8 + 4] = v1;
    }

    float O[8] = {0, 0, 0, 0, 0, 0, 0, 0};
    float m = -1e30f;
    float l = 0.0f;

    const int jr = tid / 4;          // 0..63 (key row for K/V load)
    const int jc = (tid % 4) * 16;   // 0,16,32,48

    for (int jt = 0; jt < 13; ++jt) {
        const int j0 = jt * 64;
        // ---- stage K (transposed) and V into LDS
        {
            int jrow = j0 + jr;
            if (jrow > NN - 1) jrow = NN - 1;
            size_t kbase = ((size_t)(b * NN + jrow) * 3 + 1) * DIM + h * HDIM + jc;
            size_t vbase = ((size_t)(b * NN + jrow) * 3 + 2) * DIM + h * HDIM + jc;
            float kv[16], vv[16];
#pragma unroll
            for (int i = 0; i < 4; ++i)
                *(float4*)&kv[i * 4] = *(const float4*)&qkv[kbase + i * 4];
#pragma unroll
            for (int i = 0; i < 4; ++i)
                *(float4*)&vv[i * 4] = *(const float4*)&qkv[vbase + i * 4];
            __syncthreads();  // previous iteration's consumers done
#pragma unroll
            for (int i = 0; i < 16; ++i) Kts[jc + i][jr] = kv[i];
#pragma unroll
            for (int i = 0; i < 4; ++i)
                *(float4*)&Vs[jr][jc + i * 4] = *(const float4*)&vv[i * 4];
        }
        __syncthreads();

        // ---- scores for this thread's 8 keys: j_local = c*8 + jj
        float s[8] = {0, 0, 0, 0, 0, 0, 0, 0};
#pragma unroll 8
        for (int d = 0; d < 64; ++d) {
            float q = Qs[r][d];
            float4 k0v = *(const float4*)&Kts[d][c * 8];
            float4 k1v = *(const float4*)&Kts[d][c * 8 + 4];
            s[0] += q * k0v.x; s[1] += q * k0v.y;
            s[2] += q * k0v.z; s[3] += q * k0v.w;
            s[4] += q * k1v.x; s[5] += q * k1v.y;
            s[6] += q * k1v.z; s[7] += q * k1v.w;
        }
        const int valid = NN - j0;  // >= 64 except last tile (16)
#pragma unroll
        for (int jj = 0; jj < 8; ++jj) {
            int j_local = c * 8 + jj;
            s[jj] = (j_local < valid) ? s[jj] * scale : -1e30f;
        }

        // ---- online softmax (8-lane butterfly over the row's c-lanes)
        float smax = s[0];
#pragma unroll
        for (int jj = 1; jj < 8; ++jj) smax = fmaxf(smax, s[jj]);
        smax = fmaxf(smax, __shfl_xor(smax, 1));
        smax = fmaxf(smax, __shfl_xor(smax, 2));
        smax = fmaxf(smax, __shfl_xor(smax, 4));
        const float m_new = fmaxf(m, smax);
        const float alpha = __expf(m - m_new);
        float psum = 0.0f;
#pragma unroll
        for (int jj = 0; jj < 8; ++jj) {
            float p = __expf(s[jj] - m_new);
            s[jj] = p;
            psum += p;
        }
        psum += __shfl_xor(psum, 1);
        psum += __shfl_xor(psum, 2);
        psum += __shfl_xor(psum, 4);
        l = l * alpha + psum;
        m = m_new;

        // ---- publish P row fragment, then O += P @ V
        *(float4*)&Ps[r][c * 8]     = make_float4(s[0], s[1], s[2], s[3]);
        *(float4*)&Ps[r][c * 8 + 4] = make_float4(s[4], s[5], s[6], s[7]);
        __syncthreads();

#pragma unroll
        for (int dd = 0; dd < 8; ++dd) O[dd] *= alpha;
#pragma unroll 4
        for (int j = 0; j < 64; ++j) {
            float p = Ps[r][j];
            float4 v0 = *(const float4*)&Vs[j][c * 8];
            float4 v1 = *(const float4*)&Vs[j][c * 8 + 4];
            O[0] += p * v0.x; O[1] += p * v0.y;
            O[2] += p * v0.z; O[3] += p * v0.w;
            O[4] += p * v1.x; O[5] += p * v1.y;
            O[6] += p * v1.z; O[7] += p * v1.w;
        }
    }

    // ---- epilogue: out[b, q, h*64 + d] = O[d] / l
    const int qrow = q0 + r;
    if (qrow < NN) {
        const float inv = 1.0f / l;
        size_t base = (size_t)(b * NN + qrow) * DIM + h * HDIM + c * 8;
        float4 o0 = make_float4(O[0] * inv, O[1] * inv, O[2] * inv, O[3] * inv);
        float4 o1 = make_float4(O[4] * inv, O[5] * inv, O[6] * inv, O[7] * inv);
        *(float4*)&out[base] = o0;
        *(float4*)&out[base + 4] = o1;
    }
}

// ---------------------------------------------------------------------------
extern "C" void kernel_launch(void* const* d_in, const int* in_sizes, int n_in,
                              void* d_out, int out_size, void* d_ws, size_t ws_size,
                              hipStream_t stream) {
    const float* x    = (const float*)d_in[0];
    const float* Wqkv = (const float*)d_in[1];
    const float* bqkv = (const float*)d_in[2];
    const float* Wo   = (const float*)d_in[3];
    const float* bo   = (const float*)d_in[4];
    float* out = (float*)d_out;

    float* qkv  = (float*)d_ws;                       // 12544 x 2304 f32 (115.6 MB)
    float* attn = qkv + (size_t)M_TOTAL * (3 * DIM);  // 12544 x 768 f32 (38.5 MB)

    // 1) qkv = x @ Wqkv + bqkv
    {
        dim3 grid((3 * DIM) / 128, M_TOTAL / 128);  // 18 x 98
        gemm_bias_kernel<128, 128, 8><<<grid, 256, 0, stream>>>(
            x, Wqkv, bqkv, qkv, M_TOTAL, 3 * DIM, DIM);
    }
    // 2) attention
    {
        dim3 grid((NN + 31) / 32, NHEADS, BB);  // 25 x 12 x 16
        attn_kernel<<<grid, 256, 0, stream>>>(qkv, attn);
    }
    // 3) out = attn @ Wo + bo
    {
        dim3 grid(DIM / 128, M_TOTAL / 128);  // 6 x 98
        gemm_bias_kernel<128, 128, 8><<<grid, 256, 0, stream>>>(
            attn, Wo, bo, out, M_TOTAL, DIM, DIM);
    }
}

// Round 2
// 914.405 us; speedup vs baseline: 1.7476x; 1.7476x over previous
//
#include <hip/hip_runtime.h>
#include <hip/hip_bf16.h>

#define DIM 768
#define NHEADS 12
#define HDIM 64
#define BB 16
#define NN 784
#define M_TOTAL (BB * NN)   // 12544

typedef __attribute__((ext_vector_type(8))) short bf16x8;
typedef __attribute__((ext_vector_type(4))) float f32x4;

// ---- bf16 helpers (bit-level, RNE) --------------------------------------
__device__ inline unsigned short f2bf(float f) {
    union { float f; unsigned int u; } c; c.f = f;
    unsigned int u = c.u;
    unsigned int r = (u + 0x7fffu + ((u >> 16) & 1u)) >> 16;  // RNE
    return (unsigned short)r;
}
__device__ inline float bf2f(unsigned short u) {
    union { unsigned int u; float f; } c; c.u = (unsigned int)u << 16; return c.f;
}
__device__ inline float bfbits2f(unsigned int hi16bits) {
    union { unsigned int u; float f; } c; c.u = hi16bits; return c.f;
}
__device__ inline void unpack8(uint4 raw, float* f) {
    f[0] = bfbits2f(raw.x << 16); f[1] = bfbits2f(raw.x & 0xffff0000u);
    f[2] = bfbits2f(raw.y << 16); f[3] = bfbits2f(raw.y & 0xffff0000u);
    f[4] = bfbits2f(raw.z << 16); f[5] = bfbits2f(raw.z & 0xffff0000u);
    f[6] = bfbits2f(raw.w << 16); f[7] = bfbits2f(raw.w & 0xffff0000u);
}

// ---- async global->LDS, 16B per lane ------------------------------------
typedef __attribute__((address_space(3))) unsigned int lds_uint;
typedef __attribute__((address_space(1))) const unsigned int g_uint;
__device__ inline void gload_lds16(const void* g, void* l) {
    __builtin_amdgcn_global_load_lds((g_uint*)(uintptr_t)g,
                                     (lds_uint*)(uintptr_t)l, 16, 0, 0);
}

// ---------------------------------------------------------------------------
// split f32 -> (hi, lo) bf16, elementwise
// ---------------------------------------------------------------------------
__global__ __launch_bounds__(256) void split_kernel(
    const float* __restrict__ in, ushort* __restrict__ hi,
    ushort* __restrict__ lo, int n)
{
    int i = (blockIdx.x * 256 + threadIdx.x) * 4;
    if (i >= n) return;
    float4 v = *(const float4*)&in[i];
    float f[4] = {v.x, v.y, v.z, v.w};
    union { ushort u[4]; ushort4 v4; } H, L;
#pragma unroll
    for (int j = 0; j < 4; ++j) {
        unsigned short hb = f2bf(f[j]);
        H.u[j] = hb;
        L.u[j] = f2bf(f[j] - bf2f(hb));  // exact residual in f32
    }
    *(ushort4*)&hi[i] = H.v4;
    *(ushort4*)&lo[i] = L.v4;
}

// ---------------------------------------------------------------------------
// W[K][N] f32 -> WT_hi[N][K], WT_lo[N][K] bf16 (32x32 LDS tile transpose)
// ---------------------------------------------------------------------------
__global__ __launch_bounds__(256) void transpose_split_kernel(
    const float* __restrict__ W, ushort* __restrict__ Thi,
    ushort* __restrict__ Tlo, int K, int N)
{
    __shared__ float t[32][33];
    const int n0 = blockIdx.x * 32, k0 = blockIdx.y * 32;
    const int r = threadIdx.x >> 3, c4 = (threadIdx.x & 7) * 4;
    float4 v = *(const float4*)&W[(size_t)(k0 + r) * N + n0 + c4];
    t[r][c4 + 0] = v.x; t[r][c4 + 1] = v.y;
    t[r][c4 + 2] = v.z; t[r][c4 + 3] = v.w;
    __syncthreads();
    union { ushort u[4]; ushort4 v4; } H, L;
#pragma unroll
    for (int i = 0; i < 4; ++i) {
        float f = t[c4 + i][r];
        unsigned short hb = f2bf(f);
        H.u[i] = hb;
        L.u[i] = f2bf(f - bf2f(hb));
    }
    *(ushort4*)&Thi[(size_t)(n0 + r) * K + k0 + c4] = H.v4;
    *(ushort4*)&Tlo[(size_t)(n0 + r) * K + k0 + c4] = L.v4;
}

// ---------------------------------------------------------------------------
// Split-bf16 MFMA GEMM: C[M,N] = (Ahi+Alo)[M,K] @ (Bhi+Blo)^T[N,K] + bias[N]
// A row-major [M][K], B transposed [N][K] (both K-contiguous bf16).
// 128x128 tile, BK=32 (one 16x16x32 MFMA K-step), 256 threads = 4 waves,
// each wave owns a 64x64 subtile = 4x4 MFMA tiles, 3 MFMAs per tile-pair
// (hi*hi + hi*lo + lo*hi; lo*lo ~2^-18, dropped).
// Staging via global_load_lds width=16 (m97 pattern): LDS layout [row][k]
// k-contiguous, 64B rows, dest = wave-uniform base + lane*16.
// ---------------------------------------------------------------------------
template <int OUT_BF16>
__global__ __launch_bounds__(256) void gemm_split_kernel(
    const ushort* __restrict__ Ahi, const ushort* __restrict__ Alo,
    const ushort* __restrict__ Bhi, const ushort* __restrict__ Blo,
    const float* __restrict__ bias, void* __restrict__ Cout,
    int M, int N, int K)
{
    __shared__ ushort sA[2][128 * 32];   // [hi/lo][m][k]
    __shared__ ushort sB[2][128 * 32];   // [hi/lo][n][k]

    const int tid  = threadIdx.x;
    const int wave = tid >> 6;
    const int lane = tid & 63;
    const int gm = blockIdx.y * 128;
    const int gn = blockIdx.x * 128;
    const int wm = (wave & 1) * 64;      // wave's m-origin in tile
    const int wn = (wave >> 1) * 64;     // wave's n-origin in tile
    const int quad = lane >> 4;
    const int l16  = lane & 15;

    // staging: wave w stages rows [w*32, w*32+32) of each array,
    // 2 global_load_lds per array (16 rows x 64B = 1KB per instr)
    const int r0 = wave * 32 + (lane >> 2);  // rows w*32 .. w*32+15
    const int c0 = (lane & 3) * 8;           // bf16 col: 0,8,16,24 (16B)

    f32x4 acc[4][4] = {};

    for (int k0 = 0; k0 < K; k0 += 32) {
        __syncthreads();  // prior iteration's frag reads done
        gload_lds16(Ahi + (size_t)(gm + r0) * K + k0 + c0,       &sA[0][r0 * 32 + c0]);
        gload_lds16(Ahi + (size_t)(gm + r0 + 16) * K + k0 + c0,  &sA[0][(r0 + 16) * 32 + c0]);
        gload_lds16(Alo + (size_t)(gm + r0) * K + k0 + c0,       &sA[1][r0 * 32 + c0]);
        gload_lds16(Alo + (size_t)(gm + r0 + 16) * K + k0 + c0,  &sA[1][(r0 + 16) * 32 + c0]);
        gload_lds16(Bhi + (size_t)(gn + r0) * K + k0 + c0,       &sB[0][r0 * 32 + c0]);
        gload_lds16(Bhi + (size_t)(gn + r0 + 16) * K + k0 + c0,  &sB[0][(r0 + 16) * 32 + c0]);
        gload_lds16(Blo + (size_t)(gn + r0) * K + k0 + c0,       &sB[1][r0 * 32 + c0]);
        gload_lds16(Blo + (size_t)(gn + r0 + 16) * K + k0 + c0,  &sB[1][(r0 + 16) * 32 + c0]);
        __syncthreads();  // compiler emits vmcnt(0) drain before barrier

        bf16x8 ahi[4], alo[4];
#pragma unroll
        for (int mt = 0; mt < 4; ++mt) {
            const int off = (wm + mt * 16 + l16) * 32 + quad * 8;
            ahi[mt] = *(const bf16x8*)&sA[0][off];
            alo[mt] = *(const bf16x8*)&sA[1][off];
        }
#pragma unroll
        for (int nt = 0; nt < 4; ++nt) {
            const int off = (wn + nt * 16 + l16) * 32 + quad * 8;
            bf16x8 bhi = *(const bf16x8*)&sB[0][off];
            bf16x8 blo = *(const bf16x8*)&sB[1][off];
#pragma unroll
            for (int mt = 0; mt < 4; ++mt)
                acc[mt][nt] = __builtin_amdgcn_mfma_f32_16x16x32_bf16(ahi[mt], bhi, acc[mt][nt], 0, 0, 0);
#pragma unroll
            for (int mt = 0; mt < 4; ++mt)
                acc[mt][nt] = __builtin_amdgcn_mfma_f32_16x16x32_bf16(ahi[mt], blo, acc[mt][nt], 0, 0, 0);
#pragma unroll
            for (int mt = 0; mt < 4; ++mt)
                acc[mt][nt] = __builtin_amdgcn_mfma_f32_16x16x32_bf16(alo[mt], bhi, acc[mt][nt], 0, 0, 0);
        }
    }

    // epilogue: C/D layout col=lane&15, row=quad*4+reg [m89-verified]
#pragma unroll
    for (int nt = 0; nt < 4; ++nt) {
        const int col = gn + wn + nt * 16 + l16;
        const float bv = bias[col];
#pragma unroll
        for (int mt = 0; mt < 4; ++mt) {
            f32x4 v = acc[mt][nt];
#pragma unroll
            for (int r = 0; r < 4; ++r) {
                const int row = gm + wm + mt * 16 + quad * 4 + r;
                const float o = v[r] + bv;
                if (OUT_BF16)
                    ((ushort*)Cout)[(size_t)row * N + col] = f2bf(o);
                else
                    ((float*)Cout)[(size_t)row * N + col] = o;
            }
        }
    }
}

// ---------------------------------------------------------------------------
// Flash-style attention, f32 compute, bf16 in (qkv) / bf16 hi+lo out.
// Block = 256 threads: one (batch, head, 32 q-rows). K-staging remapped to
// jr=tid&63 (stride-1 rows across wave -> 2-way transpose-write conflicts,
// free per m136) vs old 4-way.
// ---------------------------------------------------------------------------
#define ATS 68  // padded LDS stride (floats)

__global__ __launch_bounds__(256) void attn_kernel(
    const ushort* __restrict__ qkv, ushort* __restrict__ ohi,
    ushort* __restrict__ olo)
{
    const int b = blockIdx.z;
    const int h = blockIdx.y;
    const int q0 = blockIdx.x * 32;
    const int tid = threadIdx.x;
    const int r = tid / 8;   // local q row 0..31
    const int c = tid % 8;   // dim/key group 0..7

    __shared__ float Qs[32][ATS];    // [r][d]
    __shared__ float Kts[64][ATS];   // transposed: [d][j]
    __shared__ float Vs[64][ATS];    // [j][d]
    __shared__ float Ps[32][ATS];    // [r][j]

    const float scale = 0.125f;  // 1/sqrt(64)

    // ---- load Q tile (bf16 -> f32)
    {
        int qrow = q0 + r; if (qrow > NN - 1) qrow = NN - 1;
        size_t base = ((size_t)(b * NN + qrow) * 3 + 0) * DIM + h * HDIM + c * 8;
        uint4 raw = *(const uint4*)&qkv[base];
        float qf[8]; unpack8(raw, qf);
        *(float4*)&Qs[r][c * 8]     = *(float4*)&qf[0];
        *(float4*)&Qs[r][c * 8 + 4] = *(float4*)&qf[4];
    }

    float O[8] = {0, 0, 0, 0, 0, 0, 0, 0};
    float m = -1e30f;
    float l = 0.0f;

    const int jrK = tid & 63;          // K-staging: row, stride-1 across wave
    const int jcK = (tid >> 6) * 16;   // wave-uniform col group
    const int jrV = tid >> 2;          // V-staging (unchanged mapping)
    const int jcV = (tid & 3) * 16;

    for (int jt = 0; jt < 13; ++jt) {
        const int j0 = jt * 64;
        {
            int jrowK = j0 + jrK; if (jrowK > NN - 1) jrowK = NN - 1;
            int jrowV = j0 + jrV; if (jrowV > NN - 1) jrowV = NN - 1;
            size_t kbase = ((size_t)(b * NN + jrowK) * 3 + 1) * DIM + h * HDIM + jcK;
            size_t vbase = ((size_t)(b * NN + jrowV) * 3 + 2) * DIM + h * HDIM + jcV;
            uint4 kr0 = *(const uint4*)&qkv[kbase];
            uint4 kr1 = *(const uint4*)&qkv[kbase + 8];
            uint4 vr0 = *(const uint4*)&qkv[vbase];
            uint4 vr1 = *(const uint4*)&qkv[vbase + 8];
            float kf[16], vf[16];
            unpack8(kr0, kf); unpack8(kr1, kf + 8);
            unpack8(vr0, vf); unpack8(vr1, vf + 8);
            __syncthreads();  // previous iteration's consumers done
#pragma unroll
            for (int i = 0; i < 16; ++i) Kts[jcK + i][jrK] = kf[i];
#pragma unroll
            for (int i = 0; i < 4; ++i)
                *(float4*)&Vs[jrV][jcV + i * 4] = *(float4*)&vf[i * 4];
        }
        __syncthreads();

        // ---- scores: this thread's 8 keys j_local = c*8 + jj
        float s[8] = {0, 0, 0, 0, 0, 0, 0, 0};
#pragma unroll 8
        for (int d = 0; d < 64; ++d) {
            float q = Qs[r][d];
            float4 k0v = *(const float4*)&Kts[d][c * 8];
            float4 k1v = *(const float4*)&Kts[d][c * 8 + 4];
            s[0] += q * k0v.x; s[1] += q * k0v.y;
            s[2] += q * k0v.z; s[3] += q * k0v.w;
            s[4] += q * k1v.x; s[5] += q * k1v.y;
            s[6] += q * k1v.z; s[7] += q * k1v.w;
        }
        const int valid = NN - j0;
#pragma unroll
        for (int jj = 0; jj < 8; ++jj) {
            int j_local = c * 8 + jj;
            s[jj] = (j_local < valid) ? s[jj] * scale : -1e30f;
        }

        // ---- online softmax (8-lane butterfly)
        float smax = s[0];
#pragma unroll
        for (int jj = 1; jj < 8; ++jj) smax = fmaxf(smax, s[jj]);
        smax = fmaxf(smax, __shfl_xor(smax, 1));
        smax = fmaxf(smax, __shfl_xor(smax, 2));
        smax = fmaxf(smax, __shfl_xor(smax, 4));
        const float m_new = fmaxf(m, smax);
        const float alpha = __expf(m - m_new);
        float psum = 0.0f;
#pragma unroll
        for (int jj = 0; jj < 8; ++jj) {
            float p = __expf(s[jj] - m_new);
            s[jj] = p;
            psum += p;
        }
        psum += __shfl_xor(psum, 1);
        psum += __shfl_xor(psum, 2);
        psum += __shfl_xor(psum, 4);
        l = l * alpha + psum;
        m = m_new;

        *(float4*)&Ps[r][c * 8]     = make_float4(s[0], s[1], s[2], s[3]);
        *(float4*)&Ps[r][c * 8 + 4] = make_float4(s[4], s[5], s[6], s[7]);
        __syncthreads();

#pragma unroll
        for (int dd = 0; dd < 8; ++dd) O[dd] *= alpha;
#pragma unroll 4
        for (int j = 0; j < 64; ++j) {
            float p = Ps[r][j];
            float4 v0 = *(const float4*)&Vs[j][c * 8];
            float4 v1 = *(const float4*)&Vs[j][c * 8 + 4];
            O[0] += p * v0.x; O[1] += p * v0.y;
            O[2] += p * v0.z; O[3] += p * v0.w;
            O[4] += p * v1.x; O[5] += p * v1.y;
            O[6] += p * v1.z; O[7] += p * v1.w;
        }
    }

    // ---- epilogue: split hi/lo bf16 write
    const int qrow = q0 + r;
    if (qrow < NN) {
        const float inv = 1.0f / l;
        size_t base = (size_t)(b * NN + qrow) * DIM + h * HDIM + c * 8;
        union { ushort u[8]; uint4 v; } H, L;
#pragma unroll
        for (int d = 0; d < 8; ++d) {
            float o = O[d] * inv;
            unsigned short hb = f2bf(o);
            H.u[d] = hb;
            L.u[d] = f2bf(o - bf2f(hb));
        }
        *(uint4*)&ohi[base] = H.v;
        *(uint4*)&olo[base] = L.v;
    }
}

// ---------------------------------------------------------------------------
extern "C" void kernel_launch(void* const* d_in, const int* in_sizes, int n_in,
                              void* d_out, int out_size, void* d_ws, size_t ws_size,
                              hipStream_t stream) {
    const float* x    = (const float*)d_in[0];
    const float* Wqkv = (const float*)d_in[1];
    const float* bqkv = (const float*)d_in[2];
    const float* Wo   = (const float*)d_in[3];
    const float* bo   = (const float*)d_in[4];
    float* out = (float*)d_out;

    // workspace layout (all bf16/ushort), total ~106 MB (< 154 MB proven):
    char* ws = (char*)d_ws;
    ushort* qkv    = (ushort*)ws;                                   // M x 2304
    ushort* xhi    = (ushort*)(ws + (size_t)M_TOTAL * 3 * DIM * 2); // M x 768
    ushort* xlo    = xhi + (size_t)M_TOTAL * DIM;                   // M x 768
    ushort* wqT_hi = xlo + (size_t)M_TOTAL * DIM;                   // 2304 x 768
    ushort* wqT_lo = wqT_hi + (size_t)3 * DIM * DIM;
    ushort* woT_hi = wqT_lo + (size_t)3 * DIM * DIM;                // 768 x 768
    ushort* woT_lo = woT_hi + (size_t)DIM * DIM;
    // attn output hi/lo reuses x hi/lo space (x dead after GEMM1)
    ushort* athi = xhi;
    ushort* atlo = xlo;

    // 1) split x into hi/lo bf16
    {
        int n = M_TOTAL * DIM;
        split_kernel<<<(n / 4 + 255) / 256, 256, 0, stream>>>(x, xhi, xlo, n);
    }
    // 2) transpose+split weights
    transpose_split_kernel<<<dim3((3 * DIM) / 32, DIM / 32), 256, 0, stream>>>(
        Wqkv, wqT_hi, wqT_lo, DIM, 3 * DIM);
    transpose_split_kernel<<<dim3(DIM / 32, DIM / 32), 256, 0, stream>>>(
        Wo, woT_hi, woT_lo, DIM, DIM);
    // 3) qkv = x @ Wqkv + bqkv   (output bf16)
    gemm_split_kernel<1><<<dim3((3 * DIM) / 128, M_TOTAL / 128), 256, 0, stream>>>(
        xhi, xlo, wqT_hi, wqT_lo, bqkv, qkv, M_TOTAL, 3 * DIM, DIM);
    // 4) attention (bf16 in, split bf16 out)
    attn_kernel<<<dim3((NN + 31) / 32, NHEADS, BB), 256, 0, stream>>>(qkv, athi, atlo);
    // 5) out = attn @ Wo + bo    (output f32)
    gemm_split_kernel<0><<<dim3(DIM / 128, M_TOTAL / 128), 256, 0, stream>>>(
        athi, atlo, woT_hi, woT_lo, bo, out, M_TOTAL, DIM, DIM);
}

// Round 3
// 462.202 us; speedup vs baseline: 3.4573x; 1.9784x over previous
//
#include <hip/hip_runtime.h>
#include <hip/hip_bf16.h>

#define DIM 768
#define NHEADS 12
#define HDIM 64
#define BB 16
#define NN 784
#define M_TOTAL (BB * NN)   // 12544

typedef __attribute__((ext_vector_type(8))) short bf16x8;
typedef __attribute__((ext_vector_type(4))) float f32x4;

// ---- bf16 helpers (bit-level, RNE) --------------------------------------
__device__ inline unsigned short f2bf(float f) {
    union { float f; unsigned int u; } c; c.f = f;
    unsigned int u = c.u;
    unsigned int r = (u + 0x7fffu + ((u >> 16) & 1u)) >> 16;  // RNE
    return (unsigned short)r;
}
__device__ inline float bf2f(unsigned short u) {
    union { unsigned int u; float f; } c; c.u = (unsigned int)u << 16; return c.f;
}

// ---- async global->LDS, 16B per lane ------------------------------------
typedef __attribute__((address_space(3))) unsigned int lds_uint;
typedef __attribute__((address_space(1))) const unsigned int g_uint;
__device__ inline void gload_lds16(const void* g, void* l) {
    __builtin_amdgcn_global_load_lds((g_uint*)(uintptr_t)g,
                                     (lds_uint*)(uintptr_t)l, 16, 0, 0);
}

// ---------------------------------------------------------------------------
// split f32 -> (hi, lo) bf16, elementwise
// ---------------------------------------------------------------------------
__global__ __launch_bounds__(256) void split_kernel(
    const float* __restrict__ in, ushort* __restrict__ hi,
    ushort* __restrict__ lo, int n)
{
    int i = (blockIdx.x * 256 + threadIdx.x) * 4;
    if (i >= n) return;
    float4 v = *(const float4*)&in[i];
    float f[4] = {v.x, v.y, v.z, v.w};
    union { ushort u[4]; ushort4 v4; } H, L;
#pragma unroll
    for (int j = 0; j < 4; ++j) {
        unsigned short hb = f2bf(f[j]);
        H.u[j] = hb;
        L.u[j] = f2bf(f[j] - bf2f(hb));  // exact residual in f32
    }
    *(ushort4*)&hi[i] = H.v4;
    *(ushort4*)&lo[i] = L.v4;
}

// ---------------------------------------------------------------------------
// W[K][N] f32 -> WT_hi[N][K], WT_lo[N][K] bf16 (32x32 LDS tile transpose)
// ---------------------------------------------------------------------------
__global__ __launch_bounds__(256) void transpose_split_kernel(
    const float* __restrict__ W, ushort* __restrict__ Thi,
    ushort* __restrict__ Tlo, int K, int N)
{
    __shared__ float t[32][33];
    const int n0 = blockIdx.x * 32, k0 = blockIdx.y * 32;
    const int r = threadIdx.x >> 3, c4 = (threadIdx.x & 7) * 4;
    float4 v = *(const float4*)&W[(size_t)(k0 + r) * N + n0 + c4];
    t[r][c4 + 0] = v.x; t[r][c4 + 1] = v.y;
    t[r][c4 + 2] = v.z; t[r][c4 + 3] = v.w;
    __syncthreads();
    union { ushort u[4]; ushort4 v4; } H, L;
#pragma unroll
    for (int i = 0; i < 4; ++i) {
        float f = t[c4 + i][r];
        unsigned short hb = f2bf(f);
        H.u[i] = hb;
        L.u[i] = f2bf(f - bf2f(hb));
    }
    *(ushort4*)&Thi[(size_t)(n0 + r) * K + k0 + c4] = H.v4;
    *(ushort4*)&Tlo[(size_t)(n0 + r) * K + k0 + c4] = L.v4;
}

// ---------------------------------------------------------------------------
// Split-bf16 MFMA GEMM (unchanged from R2): C = (Ahi+Alo)(Bhi+Blo)^T + bias
// ---------------------------------------------------------------------------
template <int OUT_BF16>
__global__ __launch_bounds__(256) void gemm_split_kernel(
    const ushort* __restrict__ Ahi, const ushort* __restrict__ Alo,
    const ushort* __restrict__ Bhi, const ushort* __restrict__ Blo,
    const float* __restrict__ bias, void* __restrict__ Cout,
    int M, int N, int K)
{
    __shared__ ushort sA[2][128 * 32];   // [hi/lo][m][k]
    __shared__ ushort sB[2][128 * 32];   // [hi/lo][n][k]

    const int tid  = threadIdx.x;
    const int wave = tid >> 6;
    const int lane = tid & 63;
    const int gm = blockIdx.y * 128;
    const int gn = blockIdx.x * 128;
    const int wm = (wave & 1) * 64;
    const int wn = (wave >> 1) * 64;
    const int quad = lane >> 4;
    const int l16  = lane & 15;

    const int r0 = wave * 32 + (lane >> 2);
    const int c0 = (lane & 3) * 8;

    f32x4 acc[4][4] = {};

    for (int k0 = 0; k0 < K; k0 += 32) {
        __syncthreads();
        gload_lds16(Ahi + (size_t)(gm + r0) * K + k0 + c0,       &sA[0][r0 * 32 + c0]);
        gload_lds16(Ahi + (size_t)(gm + r0 + 16) * K + k0 + c0,  &sA[0][(r0 + 16) * 32 + c0]);
        gload_lds16(Alo + (size_t)(gm + r0) * K + k0 + c0,       &sA[1][r0 * 32 + c0]);
        gload_lds16(Alo + (size_t)(gm + r0 + 16) * K + k0 + c0,  &sA[1][(r0 + 16) * 32 + c0]);
        gload_lds16(Bhi + (size_t)(gn + r0) * K + k0 + c0,       &sB[0][r0 * 32 + c0]);
        gload_lds16(Bhi + (size_t)(gn + r0 + 16) * K + k0 + c0,  &sB[0][(r0 + 16) * 32 + c0]);
        gload_lds16(Blo + (size_t)(gn + r0) * K + k0 + c0,       &sB[1][r0 * 32 + c0]);
        gload_lds16(Blo + (size_t)(gn + r0 + 16) * K + k0 + c0,  &sB[1][(r0 + 16) * 32 + c0]);
        __syncthreads();

        bf16x8 ahi[4], alo[4];
#pragma unroll
        for (int mt = 0; mt < 4; ++mt) {
            const int off = (wm + mt * 16 + l16) * 32 + quad * 8;
            ahi[mt] = *(const bf16x8*)&sA[0][off];
            alo[mt] = *(const bf16x8*)&sA[1][off];
        }
#pragma unroll
        for (int nt = 0; nt < 4; ++nt) {
            const int off = (wn + nt * 16 + l16) * 32 + quad * 8;
            bf16x8 bhi = *(const bf16x8*)&sB[0][off];
            bf16x8 blo = *(const bf16x8*)&sB[1][off];
#pragma unroll
            for (int mt = 0; mt < 4; ++mt)
                acc[mt][nt] = __builtin_amdgcn_mfma_f32_16x16x32_bf16(ahi[mt], bhi, acc[mt][nt], 0, 0, 0);
#pragma unroll
            for (int mt = 0; mt < 4; ++mt)
                acc[mt][nt] = __builtin_amdgcn_mfma_f32_16x16x32_bf16(ahi[mt], blo, acc[mt][nt], 0, 0, 0);
#pragma unroll
            for (int mt = 0; mt < 4; ++mt)
                acc[mt][nt] = __builtin_amdgcn_mfma_f32_16x16x32_bf16(alo[mt], bhi, acc[mt][nt], 0, 0, 0);
        }
    }

#pragma unroll
    for (int nt = 0; nt < 4; ++nt) {
        const int col = gn + wn + nt * 16 + l16;
        const float bv = bias[col];
#pragma unroll
        for (int mt = 0; mt < 4; ++mt) {
            f32x4 v = acc[mt][nt];
#pragma unroll
            for (int r = 0; r < 4; ++r) {
                const int row = gm + wm + mt * 16 + quad * 4 + r;
                const float o = v[r] + bv;
                if (OUT_BF16)
                    ((ushort*)Cout)[(size_t)row * N + col] = f2bf(o);
                else
                    ((float*)Cout)[(size_t)row * N + col] = o;
            }
        }
    }
}

// ---------------------------------------------------------------------------
// MFMA flash attention. Block = 256 thr (4 waves) = one (b, h, 64 q-rows).
// Wave w owns S/O rows [w*16, w*16+16). j-tiles of 64 keys.
// S = Q K^T via 16x16x32 bf16 MFMA (A=Q[q][d], B=K[j][d], both d-contig).
// P split hi/lo bf16 -> LDS (C-layout -> A-layout round trip, wave-private
// rows so no barrier) -> PV via 2 MFMAs vs V^T staged [d][j].
// All LDS arrays stride 72 ushorts (=144 B = 9*16 B): b128 frag reads land
// on all 8 bank-quads (conflict-free); 16B alignment everywhere.
// ---------------------------------------------------------------------------
__global__ __launch_bounds__(256) void attn_mfma_kernel(
    const ushort* __restrict__ qkv, ushort* __restrict__ ohi,
    ushort* __restrict__ olo)
{
    const int b = blockIdx.z;
    const int h = blockIdx.y;
    const int q0 = blockIdx.x * 64;
    const int tid = threadIdx.x;
    const int wave = tid >> 6;
    const int lane = tid & 63;
    const int quad = lane >> 4;
    const int l16  = lane & 15;

    __shared__ ushort Ks[64][72];   // K tile  [j][d]
    __shared__ ushort Vt[64][72];   // V^T     [d][j]
    __shared__ ushort Ph[64][72];   // P hi    [q][j]
    __shared__ ushort Pl[64][72];   // P lo    [q][j]

    const float scale = 0.125f;  // 1/sqrt(64)

    // ---- Q A-frags from global (once): row = q0 + wave*16 + l16
    bf16x8 qfrag[2];
    {
        int qrow = q0 + wave * 16 + l16; if (qrow > NN - 1) qrow = NN - 1;
        size_t base = ((size_t)(b * NN + qrow) * 3 + 0) * DIM + h * HDIM;
        qfrag[0] = *(const bf16x8*)&qkv[base + quad * 8];
        qfrag[1] = *(const bf16x8*)&qkv[base + 32 + quad * 8];
    }

    // staging mapping: sj = row within j-tile (lane), sg = wave (uniform)
    const int sj = lane;
    const int sg = wave;

    f32x4 O[4] = {};                       // O tiles [dt], C-layout
    float mrow[4] = {-1e30f, -1e30f, -1e30f, -1e30f};  // per reg-row r
    float lrow[4] = {0.f, 0.f, 0.f, 0.f};

    for (int jt = 0; jt < 13; ++jt) {
        const int j0 = jt * 64;
        int jrow = j0 + sj; if (jrow > NN - 1) jrow = NN - 1;
        const size_t kbase = ((size_t)(b * NN + jrow) * 3 + 1) * DIM + h * HDIM;
        const size_t vbase = ((size_t)(b * NN + jrow) * 3 + 2) * DIM + h * HDIM;
        // K: wave sg loads d-chunks sg*8 and sg*8+32 for its 64 rows
        uint4 k0v = *(const uint4*)&qkv[kbase + sg * 8];
        uint4 k1v = *(const uint4*)&qkv[kbase + sg * 8 + 32];
        // V: wave sg loads d-slice sg*16 .. sg*16+15, transposes into Vt
        uint4 v0v = *(const uint4*)&qkv[vbase + sg * 16];
        uint4 v1v = *(const uint4*)&qkv[vbase + sg * 16 + 8];

        __syncthreads();  // prior iteration's frag reads done
        *(uint4*)&Ks[sj][sg * 8]      = k0v;
        *(uint4*)&Ks[sj][sg * 8 + 32] = k1v;
        {
            union { uint4 v; ushort u[8]; } a, c;
            a.v = v0v; c.v = v1v;
#pragma unroll
            for (int i = 0; i < 8; ++i) Vt[sg * 16 + i][sj] = a.u[i];
#pragma unroll
            for (int i = 0; i < 8; ++i) Vt[sg * 16 + 8 + i][sj] = c.u[i];
        }
        __syncthreads();

        // ---- S = Q K^T  (4 nt tiles x 2 k-steps)
        f32x4 s[4] = {};
#pragma unroll
        for (int nt = 0; nt < 4; ++nt) {
            bf16x8 kf0 = *(const bf16x8*)&Ks[nt * 16 + l16][quad * 8];
            bf16x8 kf1 = *(const bf16x8*)&Ks[nt * 16 + l16][32 + quad * 8];
            s[nt] = __builtin_amdgcn_mfma_f32_16x16x32_bf16(qfrag[0], kf0, s[nt], 0, 0, 0);
            s[nt] = __builtin_amdgcn_mfma_f32_16x16x32_bf16(qfrag[1], kf1, s[nt], 0, 0, 0);
        }

        // ---- online softmax. C-layout: col = nt*16+l16, row = quad*4+r.
        bool ntv[4];
#pragma unroll
        for (int nt = 0; nt < 4; ++nt) ntv[nt] = (j0 + nt * 16) < NN;

        float p[4][4];   // [nt][r]
        float alpha[4];
#pragma unroll
        for (int r = 0; r < 4; ++r) {
            float mx = -1e30f;
#pragma unroll
            for (int nt = 0; nt < 4; ++nt) {
                float sv = ntv[nt] ? s[nt][r] * scale : -1e30f;
                p[nt][r] = sv;
                mx = fmaxf(mx, sv);
            }
            mx = fmaxf(mx, __shfl_xor(mx, 1));
            mx = fmaxf(mx, __shfl_xor(mx, 2));
            mx = fmaxf(mx, __shfl_xor(mx, 4));
            mx = fmaxf(mx, __shfl_xor(mx, 8));
            const float m_new = fmaxf(mrow[r], mx);
            alpha[r] = __expf(mrow[r] - m_new);
            float rs = 0.f;
#pragma unroll
            for (int nt = 0; nt < 4; ++nt) {
                float pv = ntv[nt] ? __expf(p[nt][r] - m_new) : 0.f;
                p[nt][r] = pv;
                rs += pv;
            }
            rs += __shfl_xor(rs, 1);
            rs += __shfl_xor(rs, 2);
            rs += __shfl_xor(rs, 4);
            rs += __shfl_xor(rs, 8);
            lrow[r] = lrow[r] * alpha[r] + rs;
            mrow[r] = m_new;
        }

        // ---- P -> LDS (hi/lo split). Wave-private rows; no barrier needed.
#pragma unroll
        for (int nt = 0; nt < 4; ++nt)
#pragma unroll
            for (int r = 0; r < 4; ++r) {
                const int row = wave * 16 + quad * 4 + r;
                const int col = nt * 16 + l16;
                unsigned short hb = f2bf(p[nt][r]);
                Ph[row][col] = hb;
                Pl[row][col] = f2bf(p[nt][r] - bf2f(hb));
            }

        // ---- O = O*alpha + P V
#pragma unroll
        for (int dt = 0; dt < 4; ++dt)
#pragma unroll
            for (int r = 0; r < 4; ++r) O[dt][r] *= alpha[r];

#pragma unroll
        for (int ks = 0; ks < 2; ++ks) {
            bf16x8 ph = *(const bf16x8*)&Ph[wave * 16 + l16][ks * 32 + quad * 8];
            bf16x8 pl = *(const bf16x8*)&Pl[wave * 16 + l16][ks * 32 + quad * 8];
#pragma unroll
            for (int dt = 0; dt < 4; ++dt) {
                bf16x8 vf = *(const bf16x8*)&Vt[dt * 16 + l16][ks * 32 + quad * 8];
                O[dt] = __builtin_amdgcn_mfma_f32_16x16x32_bf16(ph, vf, O[dt], 0, 0, 0);
                O[dt] = __builtin_amdgcn_mfma_f32_16x16x32_bf16(pl, vf, O[dt], 0, 0, 0);
            }
        }
    }

    // ---- epilogue: out rows = q0 + wave*16 + quad*4 + r, col = dt*16 + l16
#pragma unroll
    for (int r = 0; r < 4; ++r) {
        const int q = q0 + wave * 16 + quad * 4 + r;
        if (q < NN) {
            const float inv = 1.0f / lrow[r];
#pragma unroll
            for (int dt = 0; dt < 4; ++dt) {
                const float o = O[dt][r] * inv;
                const size_t base = (size_t)(b * NN + q) * DIM + h * HDIM + dt * 16 + l16;
                unsigned short hb = f2bf(o);
                ohi[base] = hb;
                olo[base] = f2bf(o - bf2f(hb));
            }
        }
    }
}

// ---------------------------------------------------------------------------
extern "C" void kernel_launch(void* const* d_in, const int* in_sizes, int n_in,
                              void* d_out, int out_size, void* d_ws, size_t ws_size,
                              hipStream_t stream) {
    const float* x    = (const float*)d_in[0];
    const float* Wqkv = (const float*)d_in[1];
    const float* bqkv = (const float*)d_in[2];
    const float* Wo   = (const float*)d_in[3];
    const float* bo   = (const float*)d_in[4];
    float* out = (float*)d_out;

    char* ws = (char*)d_ws;
    ushort* qkv    = (ushort*)ws;                                   // M x 2304
    ushort* xhi    = (ushort*)(ws + (size_t)M_TOTAL * 3 * DIM * 2); // M x 768
    ushort* xlo    = xhi + (size_t)M_TOTAL * DIM;                   // M x 768
    ushort* wqT_hi = xlo + (size_t)M_TOTAL * DIM;                   // 2304 x 768
    ushort* wqT_lo = wqT_hi + (size_t)3 * DIM * DIM;
    ushort* woT_hi = wqT_lo + (size_t)3 * DIM * DIM;                // 768 x 768
    ushort* woT_lo = woT_hi + (size_t)DIM * DIM;
    ushort* athi = xhi;   // attn out reuses x hi/lo (x dead after GEMM1)
    ushort* atlo = xlo;

    {
        int n = M_TOTAL * DIM;
        split_kernel<<<(n / 4 + 255) / 256, 256, 0, stream>>>(x, xhi, xlo, n);
    }
    transpose_split_kernel<<<dim3((3 * DIM) / 32, DIM / 32), 256, 0, stream>>>(
        Wqkv, wqT_hi, wqT_lo, DIM, 3 * DIM);
    transpose_split_kernel<<<dim3(DIM / 32, DIM / 32), 256, 0, stream>>>(
        Wo, woT_hi, woT_lo, DIM, DIM);
    gemm_split_kernel<1><<<dim3((3 * DIM) / 128, M_TOTAL / 128), 256, 0, stream>>>(
        xhi, xlo, wqT_hi, wqT_lo, bqkv, qkv, M_TOTAL, 3 * DIM, DIM);
    attn_mfma_kernel<<<dim3(13, NHEADS, BB), 256, 0, stream>>>(qkv, athi, atlo);
    gemm_split_kernel<0><<<dim3(DIM / 128, M_TOTAL / 128), 256, 0, stream>>>(
        athi, atlo, woT_hi, woT_lo, bo, out, M_TOTAL, DIM, DIM);
}

// Round 4
// 318.255 us; speedup vs baseline: 5.0211x; 1.4523x over previous
//
#include <hip/hip_runtime.h>

#define DIM 768
#define NHEADS 12
#define HDIM 64
#define BB 16
#define NN 784
#define M_TOTAL (BB * NN)   // 12544

typedef __attribute__((ext_vector_type(8))) _Float16 f16x8;
typedef __attribute__((ext_vector_type(4))) float f32x4;

// ---- async global->LDS, 16B per lane ------------------------------------
typedef __attribute__((address_space(3))) unsigned int lds_uint;
typedef __attribute__((address_space(1))) const unsigned int g_uint;
__device__ inline void gload_lds16(const void* g, void* l) {
    __builtin_amdgcn_global_load_lds((g_uint*)(uintptr_t)g,
                                     (lds_uint*)(uintptr_t)l, 16, 0, 0);
}

// ---------------------------------------------------------------------------
// f32 -> f16 elementwise (x8 per thread)
// ---------------------------------------------------------------------------
__global__ __launch_bounds__(256) void cvt_f16_kernel(
    const float* __restrict__ in, _Float16* __restrict__ out, int n)
{
    int i = (blockIdx.x * 256 + threadIdx.x) * 8;
    if (i >= n) return;
    float4 a = *(const float4*)&in[i];
    float4 b = *(const float4*)&in[i + 4];
    union { _Float16 h[8]; uint4 v; } o;
    o.h[0] = (_Float16)a.x; o.h[1] = (_Float16)a.y;
    o.h[2] = (_Float16)a.z; o.h[3] = (_Float16)a.w;
    o.h[4] = (_Float16)b.x; o.h[5] = (_Float16)b.y;
    o.h[6] = (_Float16)b.z; o.h[7] = (_Float16)b.w;
    *(uint4*)&out[i] = o.v;
}

// ---------------------------------------------------------------------------
// W[K][N] f32 -> WT[N][K] f16 (32x32 LDS tile transpose)
// ---------------------------------------------------------------------------
__global__ __launch_bounds__(256) void transpose_f16_kernel(
    const float* __restrict__ W, _Float16* __restrict__ T, int K, int N)
{
    __shared__ float t[32][33];
    const int n0 = blockIdx.x * 32, k0 = blockIdx.y * 32;
    const int r = threadIdx.x >> 3, c4 = (threadIdx.x & 7) * 4;
    float4 v = *(const float4*)&W[(size_t)(k0 + r) * N + n0 + c4];
    t[r][c4 + 0] = v.x; t[r][c4 + 1] = v.y;
    t[r][c4 + 2] = v.z; t[r][c4 + 3] = v.w;
    __syncthreads();
    union { _Float16 h[4]; ushort4 v4; } o;
#pragma unroll
    for (int i = 0; i < 4; ++i) o.h[i] = (_Float16)t[c4 + i][r];
    *(ushort4*)&T[(size_t)(n0 + r) * K + k0 + c4] = o.v4;
}

// ---------------------------------------------------------------------------
// f16 MFMA GEMM (m97 shape): C[M,N] = A[M,K] @ B^T[N,K] + bias[N]
// 128x128 tile, BK=32, 256 thr = 4 waves, 4x4 16x16x32 MFMA tiles per wave.
// ---------------------------------------------------------------------------
template <int OUT_F16>
__global__ __launch_bounds__(256) void gemm_f16_kernel(
    const _Float16* __restrict__ A, const _Float16* __restrict__ B,
    const float* __restrict__ bias, void* __restrict__ Cout,
    int M, int N, int K)
{
    __shared__ _Float16 sA[128 * 32];   // [m][k]
    __shared__ _Float16 sB[128 * 32];   // [n][k]

    const int tid  = threadIdx.x;
    const int wave = tid >> 6;
    const int lane = tid & 63;
    const int gm = blockIdx.y * 128;
    const int gn = blockIdx.x * 128;
    const int wm = (wave & 1) * 64;
    const int wn = (wave >> 1) * 64;
    const int quad = lane >> 4;
    const int l16  = lane & 15;

    // staging: byte offset = wave*2048 + lane*16 (wave-uniform base + lane*16)
    const int r0 = wave * 32 + (lane >> 2);
    const int c0 = (lane & 3) * 8;

    f32x4 acc[4][4] = {};

    for (int k0 = 0; k0 < K; k0 += 32) {
        __syncthreads();
        gload_lds16(A + (size_t)(gm + r0) * K + k0 + c0,      &sA[r0 * 32 + c0]);
        gload_lds16(A + (size_t)(gm + r0 + 16) * K + k0 + c0, &sA[(r0 + 16) * 32 + c0]);
        gload_lds16(B + (size_t)(gn + r0) * K + k0 + c0,      &sB[r0 * 32 + c0]);
        gload_lds16(B + (size_t)(gn + r0 + 16) * K + k0 + c0, &sB[(r0 + 16) * 32 + c0]);
        __syncthreads();

        f16x8 a[4];
#pragma unroll
        for (int mt = 0; mt < 4; ++mt)
            a[mt] = *(const f16x8*)&sA[(wm + mt * 16 + l16) * 32 + quad * 8];
#pragma unroll
        for (int nt = 0; nt < 4; ++nt) {
            f16x8 b = *(const f16x8*)&sB[(wn + nt * 16 + l16) * 32 + quad * 8];
#pragma unroll
            for (int mt = 0; mt < 4; ++mt)
                acc[mt][nt] = __builtin_amdgcn_mfma_f32_16x16x32_f16(a[mt], b, acc[mt][nt], 0, 0, 0);
        }
    }

    // epilogue: C/D layout col=lane&15, row=quad*4+reg
#pragma unroll
    for (int nt = 0; nt < 4; ++nt) {
        const int col = gn + wn + nt * 16 + l16;
        const float bv = bias[col];
#pragma unroll
        for (int mt = 0; mt < 4; ++mt) {
            f32x4 v = acc[mt][nt];
#pragma unroll
            for (int r = 0; r < 4; ++r) {
                const int row = gm + wm + mt * 16 + quad * 4 + r;
                const float o = v[r] + bv;
                if (OUT_F16)
                    ((_Float16*)Cout)[(size_t)row * N + col] = (_Float16)o;
                else
                    ((float*)Cout)[(size_t)row * N + col] = o;
            }
        }
    }
}

// ---------------------------------------------------------------------------
// f16 MFMA flash attention. Block = 256 thr (4 waves) = one (b, h, 64 q-rows).
// Wave w owns S/O rows [w*16, w*16+16). j-tiles of 64 keys.
// scale folded into Q at load (x0.125 exact in f16).
// Vt staged via paired-row ushort2 writes: bank = lane&31 -> 2-way = free.
// LDS stride 72 f16 (144 B = 9 x 16 B): b128 frag reads conflict-free.
// ---------------------------------------------------------------------------
__global__ __launch_bounds__(256) void attn_f16_kernel(
    const _Float16* __restrict__ qkv, _Float16* __restrict__ oat)
{
    const int b = blockIdx.z;
    const int h = blockIdx.y;
    const int q0 = blockIdx.x * 64;
    const int tid = threadIdx.x;
    const int wave = tid >> 6;
    const int lane = tid & 63;
    const int quad = lane >> 4;
    const int l16  = lane & 15;

    __shared__ _Float16 Ks[64][72];   // K tile [j][d]
    __shared__ _Float16 Vt[64][72];   // V^T    [d][j]
    __shared__ _Float16 Ph[64][72];   // P      [q][j]

    // ---- Q A-frags (scaled by 1/8, exact)
    f16x8 qfrag[2];
    {
        int qrow = q0 + wave * 16 + l16; if (qrow > NN - 1) qrow = NN - 1;
        size_t base = (size_t)(b * NN + qrow) * (3 * DIM) + h * HDIM;
        f16x8 q0v = *(const f16x8*)&qkv[base + quad * 8];
        f16x8 q1v = *(const f16x8*)&qkv[base + 32 + quad * 8];
        qfrag[0] = q0v * (_Float16)0.125f;
        qfrag[1] = q1v * (_Float16)0.125f;
    }

    // K staging: lane = j row, wave = d-chunk (uniform)
    const int sj = lane;
    const int sg = wave;
    // V staging: lane -> j pair + d sub-chunk
    const int jj   = lane & 31;                  // j pair index
    const int dsub = sg * 16 + (lane >> 5) * 8;  // 8 d's

    f32x4 O[4] = {};
    float mrow[4] = {-1e30f, -1e30f, -1e30f, -1e30f};
    float lrow[4] = {0.f, 0.f, 0.f, 0.f};

    for (int jt = 0; jt < 13; ++jt) {
        const int j0 = jt * 64;
        int jrowK = j0 + sj; if (jrowK > NN - 1) jrowK = NN - 1;
        const size_t kbase = (size_t)(b * NN + jrowK) * (3 * DIM) + DIM + h * HDIM;
        uint4 k0v = *(const uint4*)&qkv[kbase + sg * 8];
        uint4 k1v = *(const uint4*)&qkv[kbase + sg * 8 + 32];

        int vr0 = j0 + 2 * jj;     if (vr0 > NN - 1) vr0 = NN - 1;
        int vr1 = j0 + 2 * jj + 1; if (vr1 > NN - 1) vr1 = NN - 1;
        const size_t vb0 = (size_t)(b * NN + vr0) * (3 * DIM) + 2 * DIM + h * HDIM + dsub;
        const size_t vb1 = (size_t)(b * NN + vr1) * (3 * DIM) + 2 * DIM + h * HDIM + dsub;
        union { uint4 v; _Float16 h[8]; } va, vc;
        va.v = *(const uint4*)&qkv[vb0];
        vc.v = *(const uint4*)&qkv[vb1];

        __syncthreads();  // prior iteration's frag reads done
        *(uint4*)&Ks[sj][sg * 8]      = k0v;
        *(uint4*)&Ks[sj][sg * 8 + 32] = k1v;
#pragma unroll
        for (int i = 0; i < 8; ++i) {
            union { _Float16 h[2]; unsigned int u; } t;
            t.h[0] = va.h[i]; t.h[1] = vc.h[i];
            *(unsigned int*)&Vt[dsub + i][2 * jj] = t.u;
        }
        __syncthreads();

        // ---- S = (Q/8) K^T
        f32x4 s[4] = {};
#pragma unroll
        for (int nt = 0; nt < 4; ++nt) {
            f16x8 kf0 = *(const f16x8*)&Ks[nt * 16 + l16][quad * 8];
            f16x8 kf1 = *(const f16x8*)&Ks[nt * 16 + l16][32 + quad * 8];
            s[nt] = __builtin_amdgcn_mfma_f32_16x16x32_f16(qfrag[0], kf0, s[nt], 0, 0, 0);
            s[nt] = __builtin_amdgcn_mfma_f32_16x16x32_f16(qfrag[1], kf1, s[nt], 0, 0, 0);
        }

        // ---- online softmax (C-layout: col = nt*16+l16, row = quad*4+r)
        bool ntv[4];
#pragma unroll
        for (int nt = 0; nt < 4; ++nt) ntv[nt] = (j0 + nt * 16) < NN;

        float p[4][4];
        float alpha[4];
#pragma unroll
        for (int r = 0; r < 4; ++r) {
            float mx = -1e30f;
#pragma unroll
            for (int nt = 0; nt < 4; ++nt) {
                float sv = ntv[nt] ? s[nt][r] : -1e30f;
                p[nt][r] = sv;
                mx = fmaxf(mx, sv);
            }
            mx = fmaxf(mx, __shfl_xor(mx, 1));
            mx = fmaxf(mx, __shfl_xor(mx, 2));
            mx = fmaxf(mx, __shfl_xor(mx, 4));
            mx = fmaxf(mx, __shfl_xor(mx, 8));
            const float m_new = fmaxf(mrow[r], mx);
            alpha[r] = __expf(mrow[r] - m_new);
            float rs = 0.f;
#pragma unroll
            for (int nt = 0; nt < 4; ++nt) {
                float pv = ntv[nt] ? __expf(p[nt][r] - m_new) : 0.f;
                p[nt][r] = pv;
                rs += pv;
            }
            rs += __shfl_xor(rs, 1);
            rs += __shfl_xor(rs, 2);
            rs += __shfl_xor(rs, 4);
            rs += __shfl_xor(rs, 8);
            lrow[r] = lrow[r] * alpha[r] + rs;
            mrow[r] = m_new;
        }

        // ---- P -> LDS (wave-private rows, no barrier needed)
#pragma unroll
        for (int nt = 0; nt < 4; ++nt)
#pragma unroll
            for (int r = 0; r < 4; ++r)
                Ph[wave * 16 + quad * 4 + r][nt * 16 + l16] = (_Float16)p[nt][r];

        // ---- O = O*alpha + P V
#pragma unroll
        for (int dt = 0; dt < 4; ++dt)
#pragma unroll
            for (int r = 0; r < 4; ++r) O[dt][r] *= alpha[r];

#pragma unroll
        for (int ks = 0; ks < 2; ++ks) {
            f16x8 ph = *(const f16x8*)&Ph[wave * 16 + l16][ks * 32 + quad * 8];
#pragma unroll
            for (int dt = 0; dt < 4; ++dt) {
                f16x8 vf = *(const f16x8*)&Vt[dt * 16 + l16][ks * 32 + quad * 8];
                O[dt] = __builtin_amdgcn_mfma_f32_16x16x32_f16(ph, vf, O[dt], 0, 0, 0);
            }
        }
    }

    // ---- epilogue: oat[token, h*64 + dt*16 + l16]
#pragma unroll
    for (int r = 0; r < 4; ++r) {
        const int q = q0 + wave * 16 + quad * 4 + r;
        if (q < NN) {
            const float inv = 1.0f / lrow[r];
#pragma unroll
            for (int dt = 0; dt < 4; ++dt) {
                const size_t base = (size_t)(b * NN + q) * DIM + h * HDIM + dt * 16 + l16;
                oat[base] = (_Float16)(O[dt][r] * inv);
            }
        }
    }
}

// ---------------------------------------------------------------------------
extern "C" void kernel_launch(void* const* d_in, const int* in_sizes, int n_in,
                              void* d_out, int out_size, void* d_ws, size_t ws_size,
                              hipStream_t stream) {
    const float* x    = (const float*)d_in[0];
    const float* Wqkv = (const float*)d_in[1];
    const float* bqkv = (const float*)d_in[2];
    const float* Wo   = (const float*)d_in[3];
    const float* bo   = (const float*)d_in[4];
    float* out = (float*)d_out;

    // workspace (f16): qkv 57.8MB, xh 19.3MB (reused as attn-out), wqT 3.5MB, woT 1.2MB
    _Float16* qkv = (_Float16*)d_ws;                    // M x 2304
    _Float16* xh  = qkv + (size_t)M_TOTAL * 3 * DIM;    // M x 768
    _Float16* wqT = xh + (size_t)M_TOTAL * DIM;         // 2304 x 768
    _Float16* woT = wqT + (size_t)3 * DIM * DIM;        // 768 x 768
    _Float16* oat = xh;  // attn out reuses xh (x dead after GEMM1)

    {
        int n = M_TOTAL * DIM;
        cvt_f16_kernel<<<n / 8 / 256, 256, 0, stream>>>(x, xh, n);
    }
    transpose_f16_kernel<<<dim3((3 * DIM) / 32, DIM / 32), 256, 0, stream>>>(
        Wqkv, wqT, DIM, 3 * DIM);
    transpose_f16_kernel<<<dim3(DIM / 32, DIM / 32), 256, 0, stream>>>(
        Wo, woT, DIM, DIM);
    gemm_f16_kernel<1><<<dim3((3 * DIM) / 128, M_TOTAL / 128), 256, 0, stream>>>(
        xh, wqT, bqkv, qkv, M_TOTAL, 3 * DIM, DIM);
    attn_f16_kernel<<<dim3(13, NHEADS, BB), 256, 0, stream>>>(qkv, oat);
    gemm_f16_kernel<0><<<dim3(DIM / 128, M_TOTAL / 128), 256, 0, stream>>>(
        oat, woT, bo, out, M_TOTAL, DIM, DIM);
}